// Round 3
// baseline (249.472 us; speedup 1.0000x reference)
//
#include <hip/hip_runtime.h>
#include <hip/hip_bf16.h>
#include <cstdint>

#define NN 384
#define OUT1OFF 196608
#define OUT2OFF 205824

typedef float f4 __attribute__((ext_vector_type(4)));
typedef short short8 __attribute__((ext_vector_type(8)));
typedef unsigned int u32;

union FragU { short8 s; u32 w[4]; };

__device__ inline unsigned short f2bf(float f) {
    u32 u = __float_as_uint(f);
    return (unsigned short)((u + 0x7fffu + ((u >> 16) & 1u)) >> 16);
}
__device__ inline u32 pkbf(float lo, float hi) {
    u32 r;
    asm("v_cvt_pk_bf16_f32 %0, %1, %2" : "=v"(r) : "v"(lo), "v"(hi));
    return r;
}
__device__ inline float siluf(float x) {
    return x * __builtin_amdgcn_rcpf(1.0f + __expf(-x));
}
__device__ inline float seluf(float x) {
    const float sc = 1.0507009873554805f, al = 1.6732632423543772f;
    return x > 0.f ? sc * x : sc * al * (__expf(x) - 1.f);
}

#define DSFENCE() do { asm volatile("s_waitcnt lgkmcnt(0)" ::: "memory"); \
                       __builtin_amdgcn_sched_barrier(0); } while (0)

// ---- prep1: HiC[row,h] = be1[h] + feats[row,:]@We1[0:64,h]
//            HjC[row,h] =          feats[row,:]@We1[64:128,h]
__global__ __launch_bounds__(128) void egnn_prep1(
    const float* __restrict__ feats, const float* __restrict__ We1,
    const float* __restrict__ be1, float* __restrict__ HiC, float* __restrict__ HjC) {
    int r0 = blockIdx.x * 8;
    int t = threadIdx.x;
    __shared__ float fr[8][64];
    for (int k = t; k < 512; k += 128) fr[k >> 6][k & 63] = feats[(size_t)r0 * 64 + k];
    __syncthreads();
    float a1[8], a2[8];
#pragma unroll
    for (int r = 0; r < 8; r++) { a1[r] = be1[t]; a2[r] = 0.f; }
    for (int d = 0; d < 64; d++) {
        float w1 = We1[d * 128 + t], w2 = We1[(64 + d) * 128 + t];
#pragma unroll
        for (int r = 0; r < 8; r++) { a1[r] += fr[r][d] * w1; a2[r] += fr[r][d] * w2; }
    }
#pragma unroll
    for (int r = 0; r < 8; r++) {
        HiC[(size_t)(r0 + r) * 128 + t] = a1[r];
        HjC[(size_t)(r0 + r) * 128 + t] = a2[r];
    }
}

// ---- prep2: pack We2^T / Wc1^T as MFMA A-fragments (weights-as-A swapped form)
__global__ __launch_bounds__(64) void egnn_prep2(
    const float* __restrict__ We2, const float* __restrict__ Wc1,
    unsigned short* __restrict__ B2P, unsigned short* __restrict__ B3P) {
    int f = blockIdx.x;
    int l = threadIdx.x;
    int g = l >> 4, cc = l & 15;
    if (f < 16) {
        int n = f >> 2, ks = f & 3;
#pragma unroll
        for (int e = 0; e < 8; e++) {
            int row = ks * 32 + 8 * g + e, col = n * 16 + cc;
            B2P[(f * 64 + l) * 8 + e] = f2bf(We2[row * 64 + col]);
        }
    } else {
        int f2 = f - 16;
        int n = f2 >> 1, k2 = f2 & 1;
#pragma unroll
        for (int e = 0; e < 8; e++) {
            int row = k2 * 32 + 8 * g + e, col = n * 16 + cc;
            B3P[(f2 * 64 + l) * 8 + e] = f2bf(Wc1[row * 64 + col]);
        }
    }
}

// ---- main: ONE WAVE per (b,i); weights in VGPR; no block barriers at all
__global__ __launch_bounds__(256, 3) void egnn_main(
    const float* __restrict__ feats, const float* __restrict__ coors,
    const float* __restrict__ vel, const float* __restrict__ edges,
    const float* __restrict__ We1,
    const float* __restrict__ be2, const float* __restrict__ bc1,
    const float* __restrict__ Wc2, const float* __restrict__ bc2,
    const float* __restrict__ Wn1, const float* __restrict__ bn1,
    const float* __restrict__ Wn2, const float* __restrict__ bn2,
    const float* __restrict__ Wv, const float* __restrict__ bv,
    const float* __restrict__ HiC, const float* __restrict__ HjC,
    const unsigned short* __restrict__ B2P, const unsigned short* __restrict__ B3P,
    float* __restrict__ out) {
    __shared__ __align__(16) short xch[4][16][136];   // per-wave exchange (rows 272B)

    const int tid = threadIdx.x;
    const int w = tid >> 6, lane = tid & 63;
    const int g = lane >> 4, c = lane & 15;

    const int flat = blockIdx.x * 4 + w;   // == b*NN + i
    const int b = flat / NN;
    const size_t bi = (size_t)flat;

    // ---- weight fragments in registers
    short8 b2f[4][4], b3f[4][2];
#pragma unroll
    for (int n = 0; n < 4; n++)
#pragma unroll
        for (int ks = 0; ks < 4; ks++)
            b2f[n][ks] = *(const short8*)(B2P + ((n * 4 + ks) * 64 + lane) * 8);
#pragma unroll
    for (int n = 0; n < 4; n++)
#pragma unroll
        for (int k2 = 0; k2 < 2; k2++)
            b3f[n][k2] = *(const short8*)(B3P + ((n * 2 + k2) * 64 + lane) * 8);

    // ---- stage-1 A-frags: k=0..4 = We1 rows 128..132 (d2, e0..3), k=5 = HiC[i][h]
    u32 w1p0[8], w1p1[8], w1p2[8];
#pragma unroll
    for (int n = 0; n < 8; n++) {
        float v0 = 0.f, v1 = 0.f, v2 = 0.f, v3 = 0.f, v4 = 0.f, v5 = 0.f;
        if (g == 0) {
            const int h = n * 16 + c;
            v0 = We1[128 * 128 + h]; v1 = We1[129 * 128 + h];
            v2 = We1[130 * 128 + h]; v3 = We1[131 * 128 + h];
            v4 = We1[132 * 128 + h];
            v5 = HiC[bi * 128 + h];
        }
        w1p0[n] = pkbf(v0, v1);
        w1p1[n] = pkbf(v2, v3);
        w1p2[n] = pkbf(v4, v5);
    }

    const float bc2v = bc2[0];
    const float ci0 = coors[bi * 3], ci1 = coors[bi * 3 + 1], ci2 = coors[bi * 3 + 2];
    const float cig = (g == 0) ? ci0 : ((g == 1) ? ci1 : ci2);

    f4 maccv[4];
#pragma unroll
    for (int n = 0; n < 4; n++) maccv[n] = (f4){0.f, 0.f, 0.f, 0.f};
    float aggp = 0.f;

    short* xrow = &xch[w][c][0];

#pragma unroll 1
    for (int jt = 0; jt < 24; ++jt) {
        const int j = jt * 16 + c;
        const float* cjp = &coors[((size_t)b * NN + j) * 3];
        const float cj0 = cjp[0], cj1 = cjp[1], cj2 = cjp[2];
        const f4 ev = *(const f4*)&edges[(bi * NN + j) * 4];
        const float* hjp = &HjC[((size_t)b * NN + j) * 128];
        f4 hjv[8];
#pragma unroll
        for (int n = 0; n < 8; n++) hjv[n] = *(const f4*)&hjp[n * 16 + 4 * g];
        const float r0 = ci0 - cj0, r1 = ci1 - cj1, r2 = ci2 - cj2;
        const float d2v = r0 * r0 + r1 * r1 + r2 * r2;

        FragU b1;
        b1.w[0] = (g == 0) ? pkbf(d2v, ev.x) : 0u;
        b1.w[1] = (g == 0) ? pkbf(ev.y, ev.z) : 0u;
        b1.w[2] = (g == 0) ? pkbf(ev.w, 1.0f) : 0u;
        b1.w[3] = 0u;

        // ---- stage 1: D = W5~·x~ (incl. HiC rank-1) + C(=HjC slice); silu; to xch
#pragma unroll
        for (int n = 0; n < 8; n++) {
            FragU a1;
            a1.w[0] = w1p0[n]; a1.w[1] = w1p1[n]; a1.w[2] = w1p2[n]; a1.w[3] = 0u;
            f4 d1 = __builtin_amdgcn_mfma_f32_16x16x32_bf16(a1.s, b1.s, hjv[n], 0, 0, 0);
            const u32 lo = pkbf(siluf(d1.x), siluf(d1.y));
            const u32 hi = pkbf(siluf(d1.z), siluf(d1.w));
            *(uint2*)&xrow[n * 16 + 4 * g] = make_uint2(lo, hi);
        }
        DSFENCE();

        // ---- stage 2: M2 = We2^T · m1^T  (+be2 via C-init from L1)
        f4 c2[4];
#pragma unroll
        for (int n = 0; n < 4; n++) c2[n] = *(const f4*)&be2[n * 16 + 4 * g];
#pragma unroll
        for (int ks = 0; ks < 4; ks++) {
            const short8 b2 = *(const short8*)&xrow[ks * 32 + 8 * g];
#pragma unroll
            for (int n = 0; n < 4; n++)
                c2[n] = __builtin_amdgcn_mfma_f32_16x16x32_bf16(b2f[n][ks], b2, c2[n], 0, 0, 0);
        }
#pragma unroll
        for (int n = 0; n < 4; n++) {
            f4 s2;
            s2.x = siluf(c2[n].x); s2.y = siluf(c2[n].y);
            s2.z = siluf(c2[n].z); s2.w = siluf(c2[n].w);
            maccv[n] += s2;
            *(uint2*)&xrow[n * 16 + 4 * g] = make_uint2(pkbf(s2.x, s2.y), pkbf(s2.z, s2.w));
        }
        DSFENCE();

        // ---- stage 3: cwh = Wc1^T · m^T (+bc1); cw = silu(cwh)·Wc2 + bc2
        f4 c3[4];
#pragma unroll
        for (int n = 0; n < 4; n++) c3[n] = *(const f4*)&bc1[n * 16 + 4 * g];
#pragma unroll
        for (int k2 = 0; k2 < 2; k2++) {
            const short8 b3 = *(const short8*)&xrow[k2 * 32 + 8 * g];
#pragma unroll
            for (int n = 0; n < 4; n++)
                c3[n] = __builtin_amdgcn_mfma_f32_16x16x32_bf16(b3f[n][k2], b3, c3[n], 0, 0, 0);
        }
        float cwp = 0.f;
#pragma unroll
        for (int n = 0; n < 4; n++) {
            const f4 wc = *(const f4*)&Wc2[n * 16 + 4 * g];
            cwp += siluf(c3[n].x) * wc.x;
            cwp += siluf(c3[n].y) * wc.y;
            cwp += siluf(c3[n].z) * wc.z;
            cwp += siluf(c3[n].w) * wc.w;
        }
        cwp += __shfl_xor(cwp, 16);
        cwp += __shfl_xor(cwp, 32);
        const float cw = cwp + bc2v;
        const float cjg = (g == 0) ? cj0 : ((g == 1) ? cj1 : cj2);
        aggp += (cig - cjg) * cw;   // valid for g<3; g==3 partial never read
    }

    // ---- per-wave epilogue (red/hid aliased onto this wave's xch)
    DSFENCE();
    float* red = (float*)&xch[w][0][0];
    float* hid = red + 128;

#pragma unroll
    for (int n = 0; n < 4; n++) {
#pragma unroll
        for (int r = 0; r < 4; r++) {
            float v = maccv[n][r];
            v += __shfl_xor(v, 1); v += __shfl_xor(v, 2);
            v += __shfl_xor(v, 4); v += __shfl_xor(v, 8);
            maccv[n][r] = v;
        }
    }
    const float fv = feats[bi * 64 + lane];
    float gp = fv * Wv[lane];
    gp += __shfl_xor(gp, 1);  gp += __shfl_xor(gp, 2);
    gp += __shfl_xor(gp, 4);  gp += __shfl_xor(gp, 8);
    gp += __shfl_xor(gp, 16); gp += __shfl_xor(gp, 32);
    const float sgate = gp + bv[0];

    float aggr = aggp;
    aggr += __shfl_xor(aggr, 1); aggr += __shfl_xor(aggr, 2);
    aggr += __shfl_xor(aggr, 4); aggr += __shfl_xor(aggr, 8);

    red[lane] = fv;
    if (c == 0) {
#pragma unroll
        for (int n = 0; n < 4; n++)
            *(f4*)&red[64 + n * 16 + 4 * g] = maccv[n];
    }
    DSFENCE();

    // node MLP: hid = silu([h|m_i]@Wn1+bn1); out = h + hid@Wn2+bn2
    float a0 = bn1[lane], a1 = bn1[64 + lane];
#pragma unroll 4
    for (int k0 = 0; k0 < 128; k0 += 4) {
        const f4 rv = *(const f4*)&red[k0];
#pragma unroll
        for (int kk = 0; kk < 4; kk++) {
            const float* wr = &Wn1[(size_t)(k0 + kk) * 128];
            a0 += rv[kk] * wr[lane];
            a1 += rv[kk] * wr[64 + lane];
        }
    }
    hid[lane] = siluf(a0);
    hid[64 + lane] = siluf(a1);
    DSFENCE();
    float o = bn2[lane];
#pragma unroll 4
    for (int k0 = 0; k0 < 128; k0 += 4) {
        const f4 hv = *(const f4*)&hid[k0];
#pragma unroll
        for (int kk = 0; kk < 4; kk++)
            o += hv[kk] * Wn2[(size_t)(k0 + kk) * 64 + lane];
    }
    out[bi * 64 + lane] = fv + o;

    if (c == 0 && g < 3) {
        const size_t base = bi * 3 + g;
        const float vn = sgate * vel[base] + aggr * (1.f / 384.f);
        const float cn = coors[base] + vn;
        out[OUT1OFF + base] = seluf(cn);
        out[OUT2OFF + base] = seluf(vn);
    }
}

extern "C" void kernel_launch(void* const* d_in, const int* in_sizes, int n_in,
                              void* d_out, int out_size, void* d_ws, size_t ws_size,
                              hipStream_t stream) {
    const float* feats = (const float*)d_in[0];
    const float* coors = (const float*)d_in[1];
    const float* vel   = (const float*)d_in[2];
    const float* edges = (const float*)d_in[3];
    const float* We1   = (const float*)d_in[4];
    const float* be1   = (const float*)d_in[5];
    const float* We2   = (const float*)d_in[6];
    const float* be2   = (const float*)d_in[7];
    const float* Wc1   = (const float*)d_in[8];
    const float* bc1   = (const float*)d_in[9];
    const float* Wc2   = (const float*)d_in[10];
    const float* bc2   = (const float*)d_in[11];
    const float* Wn1   = (const float*)d_in[12];
    const float* bn1   = (const float*)d_in[13];
    const float* Wn2   = (const float*)d_in[14];
    const float* bn2   = (const float*)d_in[15];
    const float* Wv    = (const float*)d_in[16];
    const float* bv    = (const float*)d_in[17];

    float* HiC = (float*)d_ws;                              // 393216 f32
    float* HjC = HiC + 393216;                              // 393216 f32
    unsigned short* B2P = (unsigned short*)(HjC + 393216);  // 8192 u16
    unsigned short* B3P = B2P + 8192;                       // 4096 u16
    float* out = (float*)d_out;

    egnn_prep1<<<384, 128, 0, stream>>>(feats, We1, be1, HiC, HjC);
    egnn_prep2<<<24, 64, 0, stream>>>(We2, Wc1, B2P, B3P);
    egnn_main<<<768, 256, 0, stream>>>(feats, coors, vel, edges, We1,
                                       be2, bc1, Wc2, bc2, Wn1, bn1, Wn2, bn2,
                                       Wv, bv, HiC, HjC, B2P, B3P, out);
}

// Round 4
// 144.447 us; speedup vs baseline: 1.7271x; 1.7271x over previous
//
#include <hip/hip_runtime.h>
#include <hip/hip_bf16.h>
#include <cstdint>

#define NN 384
#define OUT1OFF 196608
#define OUT2OFF 205824

typedef float f4 __attribute__((ext_vector_type(4)));
typedef short short8 __attribute__((ext_vector_type(8)));
typedef unsigned int u32;

union FragU { short8 s; u32 w[4]; };

__device__ inline unsigned short f2bf(float f) {
    u32 u = __float_as_uint(f);
    return (unsigned short)((u + 0x7fffu + ((u >> 16) & 1u)) >> 16);
}
__device__ inline u32 pkbf(float lo, float hi) {
    u32 r;
    asm("v_cvt_pk_bf16_f32 %0, %1, %2" : "=v"(r) : "v"(lo), "v"(hi));
    return r;
}
__device__ inline float siluf(float x) {
    return x * __builtin_amdgcn_rcpf(1.0f + __expf(-x));
}
__device__ inline float seluf(float x) {
    const float sc = 1.0507009873554805f, al = 1.6732632423543772f;
    return x > 0.f ? sc * x : sc * al * (__expf(x) - 1.f);
}

#define DSFENCE() do { asm volatile("s_waitcnt lgkmcnt(0)" ::: "memory"); \
                       __builtin_amdgcn_sched_barrier(0); } while (0)

// ---- prep1: HiC[row,h] = be1[h] + feats[row,:]@We1[0:64,h]
//            HjC[row,h] =          feats[row,:]@We1[64:128,h]
__global__ __launch_bounds__(128) void egnn_prep1(
    const float* __restrict__ feats, const float* __restrict__ We1,
    const float* __restrict__ be1, float* __restrict__ HiC, float* __restrict__ HjC) {
    int r0 = blockIdx.x * 8;
    int t = threadIdx.x;
    __shared__ float fr[8][64];
    for (int k = t; k < 512; k += 128) fr[k >> 6][k & 63] = feats[(size_t)r0 * 64 + k];
    __syncthreads();
    float a1[8], a2[8];
#pragma unroll
    for (int r = 0; r < 8; r++) { a1[r] = be1[t]; a2[r] = 0.f; }
    for (int d = 0; d < 64; d++) {
        float w1 = We1[d * 128 + t], w2 = We1[(64 + d) * 128 + t];
#pragma unroll
        for (int r = 0; r < 8; r++) { a1[r] += fr[r][d] * w1; a2[r] += fr[r][d] * w2; }
    }
#pragma unroll
    for (int r = 0; r < 8; r++) {
        HiC[(size_t)(r0 + r) * 128 + t] = a1[r];
        HjC[(size_t)(r0 + r) * 128 + t] = a2[r];
    }
}

// ---- prep2: pack We2^T / Wc1^T as MFMA A-fragments (weights-as-A swapped form)
__global__ __launch_bounds__(64) void egnn_prep2(
    const float* __restrict__ We2, const float* __restrict__ Wc1,
    unsigned short* __restrict__ B2P, unsigned short* __restrict__ B3P) {
    int f = blockIdx.x;
    int l = threadIdx.x;
    int g = l >> 4, cc = l & 15;
    if (f < 16) {
        int n = f >> 2, ks = f & 3;
#pragma unroll
        for (int e = 0; e < 8; e++) {
            int row = ks * 32 + 8 * g + e, col = n * 16 + cc;
            B2P[(f * 64 + l) * 8 + e] = f2bf(We2[row * 64 + col]);
        }
    } else {
        int f2 = f - 16;
        int n = f2 >> 1, k2 = f2 & 1;
#pragma unroll
        for (int e = 0; e < 8; e++) {
            int row = k2 * 32 + 8 * g + e, col = n * 16 + cc;
            B3P[(f2 * 64 + l) * 8 + e] = f2bf(Wc1[row * 64 + col]);
        }
    }
}

// ---- main: ONE WAVE per (b,i); weights in VGPR; launch_bounds(256,2) => no spill
__global__ __launch_bounds__(256, 2) void egnn_main(
    const float* __restrict__ feats, const float* __restrict__ coors,
    const float* __restrict__ vel, const float* __restrict__ edges,
    const float* __restrict__ We1,
    const float* __restrict__ be2, const float* __restrict__ bc1,
    const float* __restrict__ Wc2, const float* __restrict__ bc2,
    const float* __restrict__ Wn1, const float* __restrict__ bn1,
    const float* __restrict__ Wn2, const float* __restrict__ bn2,
    const float* __restrict__ Wv, const float* __restrict__ bv,
    const float* __restrict__ HiC, const float* __restrict__ HjC,
    const unsigned short* __restrict__ B2P, const unsigned short* __restrict__ B3P,
    float* __restrict__ out) {
    __shared__ __align__(16) short xch[4][16][136];   // per-wave exchange (rows 272B)

    const int tid = threadIdx.x;
    const int w = tid >> 6, lane = tid & 63;
    const int g = lane >> 4, c = lane & 15;

    // XCD-chunked bijective swizzle: XCD k owns blocks k*96..k*96+95 == batch k
    const int blk = blockIdx.x;
    const int sw = (blk & 7) * 96 + (blk >> 3);
    const int flat = sw * 4 + w;   // == b*NN + i
    const int b = flat / NN;
    const size_t bi = (size_t)flat;

    // ---- weight fragments in registers (96 VGPR)
    short8 b2f[4][4], b3f[4][2];
#pragma unroll
    for (int n = 0; n < 4; n++)
#pragma unroll
        for (int ks = 0; ks < 4; ks++)
            b2f[n][ks] = *(const short8*)(B2P + ((n * 4 + ks) * 64 + lane) * 8);
#pragma unroll
    for (int n = 0; n < 4; n++)
#pragma unroll
        for (int k2 = 0; k2 < 2; k2++)
            b3f[n][k2] = *(const short8*)(B3P + ((n * 2 + k2) * 64 + lane) * 8);

    // ---- stage-1 A-frags: k=0..4 = We1 rows 128..132 (d2, e0..3), k=5 = HiC[i][h]
    u32 w1p0[8], w1p1[8], w1p2[8];
#pragma unroll
    for (int n = 0; n < 8; n++) {
        float v0 = 0.f, v1 = 0.f, v2 = 0.f, v3 = 0.f, v4 = 0.f, v5 = 0.f;
        if (g == 0) {
            const int h = n * 16 + c;
            v0 = We1[128 * 128 + h]; v1 = We1[129 * 128 + h];
            v2 = We1[130 * 128 + h]; v3 = We1[131 * 128 + h];
            v4 = We1[132 * 128 + h];
            v5 = HiC[bi * 128 + h];
        }
        w1p0[n] = pkbf(v0, v1);
        w1p1[n] = pkbf(v2, v3);
        w1p2[n] = pkbf(v4, v5);
    }

    const float bc2v = bc2[0];
    const float ci0 = coors[bi * 3], ci1 = coors[bi * 3 + 1], ci2 = coors[bi * 3 + 2];
    const float cig = (g == 0) ? ci0 : ((g == 1) ? ci1 : ci2);

    f4 maccv[4];
#pragma unroll
    for (int n = 0; n < 4; n++) maccv[n] = (f4){0.f, 0.f, 0.f, 0.f};
    float aggp = 0.f;

    short* xrow = &xch[w][c][0];

#pragma unroll 1
    for (int jt = 0; jt < 24; ++jt) {
        const int j = jt * 16 + c;
        const float* cjp = &coors[((size_t)b * NN + j) * 3];
        const float cj0 = cjp[0], cj1 = cjp[1], cj2 = cjp[2];
        const f4 ev = *(const f4*)&edges[(bi * NN + j) * 4];
        const float* hjp = &HjC[((size_t)b * NN + j) * 128];
        const float r0 = ci0 - cj0, r1 = ci1 - cj1, r2 = ci2 - cj2;
        const float d2v = r0 * r0 + r1 * r1 + r2 * r2;

        FragU b1;
        b1.w[0] = (g == 0) ? pkbf(d2v, ev.x) : 0u;
        b1.w[1] = (g == 0) ? pkbf(ev.y, ev.z) : 0u;
        b1.w[2] = (g == 0) ? pkbf(ev.w, 1.0f) : 0u;
        b1.w[3] = 0u;

        // ---- stage 1: D = W5~·x~ (incl. HiC rank-1) + C(=HjC slice, direct load); silu
#pragma unroll
        for (int n = 0; n < 8; n++) {
            FragU a1;
            a1.w[0] = w1p0[n]; a1.w[1] = w1p1[n]; a1.w[2] = w1p2[n]; a1.w[3] = 0u;
            const f4 hcn = *(const f4*)&hjp[n * 16 + 4 * g];
            f4 d1 = __builtin_amdgcn_mfma_f32_16x16x32_bf16(a1.s, b1.s, hcn, 0, 0, 0);
            const u32 lo = pkbf(siluf(d1.x), siluf(d1.y));
            const u32 hi = pkbf(siluf(d1.z), siluf(d1.w));
            *(uint2*)&xrow[n * 16 + 4 * g] = make_uint2(lo, hi);
        }
        DSFENCE();

        // ---- stage 2: M2 = We2^T · m1^T  (+be2 via C-init)
        f4 c2[4];
#pragma unroll
        for (int n = 0; n < 4; n++) c2[n] = *(const f4*)&be2[n * 16 + 4 * g];
#pragma unroll
        for (int ks = 0; ks < 4; ks++) {
            const short8 b2 = *(const short8*)&xrow[ks * 32 + 8 * g];
#pragma unroll
            for (int n = 0; n < 4; n++)
                c2[n] = __builtin_amdgcn_mfma_f32_16x16x32_bf16(b2f[n][ks], b2, c2[n], 0, 0, 0);
        }
#pragma unroll
        for (int n = 0; n < 4; n++) {
            f4 s2;
            s2.x = siluf(c2[n].x); s2.y = siluf(c2[n].y);
            s2.z = siluf(c2[n].z); s2.w = siluf(c2[n].w);
            maccv[n] += s2;
            *(uint2*)&xrow[n * 16 + 4 * g] = make_uint2(pkbf(s2.x, s2.y), pkbf(s2.z, s2.w));
        }
        DSFENCE();

        // ---- stage 3: cwh = Wc1^T · m^T (+bc1); cw = silu(cwh)·Wc2 + bc2
        f4 c3[4];
#pragma unroll
        for (int n = 0; n < 4; n++) c3[n] = *(const f4*)&bc1[n * 16 + 4 * g];
#pragma unroll
        for (int k2 = 0; k2 < 2; k2++) {
            const short8 b3 = *(const short8*)&xrow[k2 * 32 + 8 * g];
#pragma unroll
            for (int n = 0; n < 4; n++)
                c3[n] = __builtin_amdgcn_mfma_f32_16x16x32_bf16(b3f[n][k2], b3, c3[n], 0, 0, 0);
        }
        float cwp = 0.f;
#pragma unroll
        for (int n = 0; n < 4; n++) {
            const f4 wc = *(const f4*)&Wc2[n * 16 + 4 * g];
            cwp += siluf(c3[n].x) * wc.x;
            cwp += siluf(c3[n].y) * wc.y;
            cwp += siluf(c3[n].z) * wc.z;
            cwp += siluf(c3[n].w) * wc.w;
        }
        cwp += __shfl_xor(cwp, 16);
        cwp += __shfl_xor(cwp, 32);
        const float cw = cwp + bc2v;
        const float cjg = (g == 0) ? cj0 : ((g == 1) ? cj1 : cj2);
        aggp += (cig - cjg) * cw;   // valid for g<3; g==3 partial never read
    }

    // ---- per-wave epilogue (red/hid aliased onto this wave's xch)
    DSFENCE();
    float* red = (float*)&xch[w][0][0];
    float* hid = red + 128;

#pragma unroll
    for (int n = 0; n < 4; n++) {
#pragma unroll
        for (int r = 0; r < 4; r++) {
            float v = maccv[n][r];
            v += __shfl_xor(v, 1); v += __shfl_xor(v, 2);
            v += __shfl_xor(v, 4); v += __shfl_xor(v, 8);
            maccv[n][r] = v;
        }
    }
    const float fv = feats[bi * 64 + lane];
    float gp = fv * Wv[lane];
    gp += __shfl_xor(gp, 1);  gp += __shfl_xor(gp, 2);
    gp += __shfl_xor(gp, 4);  gp += __shfl_xor(gp, 8);
    gp += __shfl_xor(gp, 16); gp += __shfl_xor(gp, 32);
    const float sgate = gp + bv[0];

    float aggr = aggp;
    aggr += __shfl_xor(aggr, 1); aggr += __shfl_xor(aggr, 2);
    aggr += __shfl_xor(aggr, 4); aggr += __shfl_xor(aggr, 8);

    red[lane] = fv;
    if (c == 0) {
#pragma unroll
        for (int n = 0; n < 4; n++)
            *(f4*)&red[64 + n * 16 + 4 * g] = maccv[n];
    }
    DSFENCE();

    // node MLP: hid = silu([h|m_i]@Wn1+bn1); out = h + hid@Wn2+bn2
    float a0 = bn1[lane], a1 = bn1[64 + lane];
#pragma unroll 4
    for (int k0 = 0; k0 < 128; k0 += 4) {
        const f4 rv = *(const f4*)&red[k0];
#pragma unroll
        for (int kk = 0; kk < 4; kk++) {
            const float* wr = &Wn1[(size_t)(k0 + kk) * 128];
            a0 += rv[kk] * wr[lane];
            a1 += rv[kk] * wr[64 + lane];
        }
    }
    hid[lane] = siluf(a0);
    hid[64 + lane] = siluf(a1);
    DSFENCE();
    float o = bn2[lane];
#pragma unroll 4
    for (int k0 = 0; k0 < 128; k0 += 4) {
        const f4 hv = *(const f4*)&hid[k0];
#pragma unroll
        for (int kk = 0; kk < 4; kk++)
            o += hv[kk] * Wn2[(size_t)(k0 + kk) * 64 + lane];
    }
    out[bi * 64 + lane] = fv + o;

    if (c == 0 && g < 3) {
        const size_t base = bi * 3 + g;
        const float vn = sgate * vel[base] + aggr * (1.f / 384.f);
        const float cn = coors[base] + vn;
        out[OUT1OFF + base] = seluf(cn);
        out[OUT2OFF + base] = seluf(vn);
    }
}

extern "C" void kernel_launch(void* const* d_in, const int* in_sizes, int n_in,
                              void* d_out, int out_size, void* d_ws, size_t ws_size,
                              hipStream_t stream) {
    const float* feats = (const float*)d_in[0];
    const float* coors = (const float*)d_in[1];
    const float* vel   = (const float*)d_in[2];
    const float* edges = (const float*)d_in[3];
    const float* We1   = (const float*)d_in[4];
    const float* be1   = (const float*)d_in[5];
    const float* We2   = (const float*)d_in[6];
    const float* be2   = (const float*)d_in[7];
    const float* Wc1   = (const float*)d_in[8];
    const float* bc1   = (const float*)d_in[9];
    const float* Wc2   = (const float*)d_in[10];
    const float* bc2   = (const float*)d_in[11];
    const float* Wn1   = (const float*)d_in[12];
    const float* bn1   = (const float*)d_in[13];
    const float* Wn2   = (const float*)d_in[14];
    const float* bn2   = (const float*)d_in[15];
    const float* Wv    = (const float*)d_in[16];
    const float* bv    = (const float*)d_in[17];

    float* HiC = (float*)d_ws;                              // 393216 f32
    float* HjC = HiC + 393216;                              // 393216 f32
    unsigned short* B2P = (unsigned short*)(HjC + 393216);  // 8192 u16
    unsigned short* B3P = B2P + 8192;                       // 4096 u16
    float* out = (float*)d_out;

    egnn_prep1<<<384, 128, 0, stream>>>(feats, We1, be1, HiC, HjC);
    egnn_prep2<<<24, 64, 0, stream>>>(We2, Wc1, B2P, B3P);
    egnn_main<<<768, 256, 0, stream>>>(feats, coors, vel, edges, We1,
                                       be2, bc1, Wc2, bc2, Wn1, bn1, Wn2, bn2,
                                       Wv, bv, HiC, HjC, B2P, B3P, out);
}